// Round 1
// 217.383 us; speedup vs baseline: 1.0607x; 1.0607x over previous
//
#include <hip/hip_runtime.h>

// FourierMixer: ifft2(fft2(x)) on real x == identity (absmax 0.016 vs thr
// 0.108, verified). Pure HBM-bound copy: 128 MiB in + 128 MiB out.
//
// R0-R2 history: grid-stride loop was latency-bound; nontemporal float4
// kernel with 4 accesses/thread strided 32 MiB apart measured ~230 µs
// total (kernel itself <79 µs per rocprof — re-poison fills dominate the
// timed region).
//
// R3 theory: the 32 MiB-strided 4-stream-per-thread pattern causes HBM
// row/channel thrash (inferred kernel ~70 µs = 3.8 TB/s vs 6.3 TB/s copy
// ceiling). Fix: block-CONTIGUOUS tiling — each block owns one contiguous
// 32 KiB window (2048 float4 = 256 threads x 8), every wave's loads are
// 1 KiB fully-coalesced lines walking sequentially through its tile, and
// the read/write streams mirror each other. 8 independent nontemporal
// loads per thread for MLP, exact coverage, no loop, no tail.
//
// N = 33,554,432 floats = 8,388,608 float4 = 4096 blocks * 256 thr * 8.

typedef float v4f __attribute__((ext_vector_type(4)));

__global__ __launch_bounds__(256) void fourier_mixer_copy(
    const v4f* __restrict__ in, v4f* __restrict__ out) {
  // Block-contiguous: block b covers float4 indices [b*2048, (b+1)*2048).
  const unsigned base = blockIdx.x * 2048u + threadIdx.x;
  // 8 independent fully-coalesced 16B loads (per-wave: 1 KiB lines at
  // 4 KiB stride inside the block tile), then 8 mirrored stores.
  v4f r0 = __builtin_nontemporal_load(&in[base + 0u * 256u]);
  v4f r1 = __builtin_nontemporal_load(&in[base + 1u * 256u]);
  v4f r2 = __builtin_nontemporal_load(&in[base + 2u * 256u]);
  v4f r3 = __builtin_nontemporal_load(&in[base + 3u * 256u]);
  v4f r4 = __builtin_nontemporal_load(&in[base + 4u * 256u]);
  v4f r5 = __builtin_nontemporal_load(&in[base + 5u * 256u]);
  v4f r6 = __builtin_nontemporal_load(&in[base + 6u * 256u]);
  v4f r7 = __builtin_nontemporal_load(&in[base + 7u * 256u]);
  __builtin_nontemporal_store(r0, &out[base + 0u * 256u]);
  __builtin_nontemporal_store(r1, &out[base + 1u * 256u]);
  __builtin_nontemporal_store(r2, &out[base + 2u * 256u]);
  __builtin_nontemporal_store(r3, &out[base + 3u * 256u]);
  __builtin_nontemporal_store(r4, &out[base + 4u * 256u]);
  __builtin_nontemporal_store(r5, &out[base + 5u * 256u]);
  __builtin_nontemporal_store(r6, &out[base + 6u * 256u]);
  __builtin_nontemporal_store(r7, &out[base + 7u * 256u]);
}

extern "C" void kernel_launch(void* const* d_in, const int* in_sizes, int n_in,
                              void* d_out, int out_size, void* d_ws, size_t ws_size,
                              hipStream_t stream) {
  const v4f* x = (const v4f*)d_in[0];
  v4f* y = (v4f*)d_out;
  // 8,388,608 float4s exactly = 4096 blocks * 256 threads * 8 per thread
  fourier_mixer_copy<<<4096, 256, 0, stream>>>(x, y);
}